// Round 3
// baseline (154.280 us; speedup 1.0000x reference)
//
#include <hip/hip_runtime.h>

typedef float vf4 __attribute__((ext_vector_type(4)));

// 4 windows (12 contiguous columns) per thread: all global accesses become
// 16B-aligned dwordx4 (row start multiple of 1536B, group offset 48B*g).
__global__ __launch_bounds__(256) void lbp_min_rot4(
    const float* __restrict__ x, float* __restrict__ out) {
    const int g = blockIdx.x * blockDim.x + threadIdx.x;  // 2097152 groups

    // Geometry: (B*C)=512 images, OH=OW=128, 32 groups of 4 windows per row.
    const int ojg = g & 31;
    const int oi  = (g >> 5) & 127;
    const int bc  = g >> 12;
    const long base = ((long)bc * 384 + 3L * oi) * 384 + 12L * ojg;

    const float* p = x + base;
    float r0[12], r1[12], r2[12];
    *(vf4*)&r0[0] = __builtin_nontemporal_load((const vf4*)(p));
    *(vf4*)&r0[4] = __builtin_nontemporal_load((const vf4*)(p + 4));
    *(vf4*)&r0[8] = __builtin_nontemporal_load((const vf4*)(p + 8));
    *(vf4*)&r1[0] = __builtin_nontemporal_load((const vf4*)(p + 384));
    *(vf4*)&r1[4] = __builtin_nontemporal_load((const vf4*)(p + 388));
    *(vf4*)&r1[8] = __builtin_nontemporal_load((const vf4*)(p + 392));
    *(vf4*)&r2[0] = __builtin_nontemporal_load((const vf4*)(p + 768));
    *(vf4*)&r2[4] = __builtin_nontemporal_load((const vf4*)(p + 772));
    *(vf4*)&r2[8] = __builtin_nontemporal_load((const vf4*)(p + 776));

    float o0[12], o1[12], o2[12];

#pragma unroll
    for (int w = 0; w < 4; ++w) {
        const int s = 3 * w;
        const float w00 = r0[s], w01 = r0[s + 1], w02 = r0[s + 2];
        const float w10 = r1[s], w11 = r1[s + 1], w12 = r1[s + 2];
        const float w20 = r2[s], w21 = r2[s + 1], w22 = r2[s + 2];

        const float c = w11;
        const int b00 = w00 >= c, b01 = w01 >= c, b02 = w02 >= c;
        const int b10 = w10 >= c,                 b12 = w12 >= c;
        const int b20 = w20 >= c, b21 = w21 >= c, b22 = w22 >= c;

        // LBP keys of the 4 rotations (weights [[1,2,4],[8,0,16],[32,64,128]]).
        const int k0 = b00 + b01*2 + b02*4 + b10*8 + b12*16 + b20*32 + b21*64 + b22*128;
        const int k1 = b02 + b12*2 + b22*4 + b01*8 + b21*16 + b00*32 + b10*64 + b20*128;
        const int k2 = b22 + b21*2 + b20*4 + b12*8 + b10*16 + b02*32 + b01*64 + b00*128;
        const int k3 = b20 + b10*2 + b00*4 + b21*8 + b01*16 + b22*32 + b12*64 + b02*128;

        // First-occurrence argmin (matches jnp.argmin tie-breaking).
        int idx = 0, km = k0;
        if (k1 < km) { km = k1; idx = 1; }
        if (k2 < km) { km = k2; idx = 2; }
        if (k3 < km) { km = k3; idx = 3; }

#define SEL4(a, b, cc, d) (idx == 0 ? (a) : idx == 1 ? (b) : idx == 2 ? (cc) : (d))
        o0[s]     = SEL4(w00, w02, w22, w20);
        o0[s + 1] = SEL4(w01, w12, w21, w10);
        o0[s + 2] = SEL4(w02, w22, w20, w00);
        o1[s]     = SEL4(w10, w01, w12, w21);
        o1[s + 1] = w11;
        o1[s + 2] = SEL4(w12, w21, w10, w01);
        o2[s]     = SEL4(w20, w00, w02, w22);
        o2[s + 1] = SEL4(w21, w10, w01, w12);
        o2[s + 2] = SEL4(w22, w20, w00, w02);
#undef SEL4
    }

    float* q = out + base;
    __builtin_nontemporal_store(*(const vf4*)&o0[0], (vf4*)(q));
    __builtin_nontemporal_store(*(const vf4*)&o0[4], (vf4*)(q + 4));
    __builtin_nontemporal_store(*(const vf4*)&o0[8], (vf4*)(q + 8));
    __builtin_nontemporal_store(*(const vf4*)&o1[0], (vf4*)(q + 384));
    __builtin_nontemporal_store(*(const vf4*)&o1[4], (vf4*)(q + 388));
    __builtin_nontemporal_store(*(const vf4*)&o1[8], (vf4*)(q + 392));
    __builtin_nontemporal_store(*(const vf4*)&o2[0], (vf4*)(q + 768));
    __builtin_nontemporal_store(*(const vf4*)&o2[4], (vf4*)(q + 772));
    __builtin_nontemporal_store(*(const vf4*)&o2[8], (vf4*)(q + 776));
}

extern "C" void kernel_launch(void* const* d_in, const int* in_sizes, int n_in,
                              void* d_out, int out_size, void* d_ws, size_t ws_size,
                              hipStream_t stream) {
    const float* x = (const float*)d_in[0];
    float* out = (float*)d_out;
    const int total = in_sizes[0];          // 8*64*384*384 = 75497472
    const int ngroups = total / 9 / 4;      // 2097152 groups of 4 windows
    const int block = 256;
    const int grid = (ngroups + block - 1) / block;  // 8192
    lbp_min_rot4<<<grid, block, 0, stream>>>(x, out);
}

// Round 4
// 97.285 us; speedup vs baseline: 1.5858x; 1.5858x over previous
//
#include <hip/hip_runtime.h>

typedef float vf4 __attribute__((ext_vector_type(4)));

// Block b owns the contiguous flat range [b*2304, (b+1)*2304) = 6 image rows
// (2 window-rows x 128 windows). Stage in/out with fully-coalesced dwordx4;
// each thread computes one exclusive 3x3 window in LDS.
__global__ __launch_bounds__(256) void lbp_lds(
    const float* __restrict__ x, float* __restrict__ out) {
    __shared__ float tile[2304];  // 6 rows x 384 cols = 9216 B

    const int t = threadIdx.x;
    const long base = (long)blockIdx.x * 2304;

    // ---- stage in: 576 float4, coalesced ----
    const vf4* pv = (const vf4*)(x + base);
    vf4* lv = (vf4*)tile;
    lv[t]       = pv[t];
    lv[t + 256] = pv[t + 256];
    if (t < 64) lv[t + 512] = pv[t + 512];
    __syncthreads();

    // ---- compute: thread t owns window (wr = t>>7, wc = t&127) ----
    const int wr = t >> 7;
    const int wc = t & 127;
    float* wp = tile + wr * 3 * 384 + wc * 3;
    const float w00 = wp[0],   w01 = wp[1],   w02 = wp[2];
    const float w10 = wp[384], w11 = wp[385], w12 = wp[386];
    const float w20 = wp[768], w21 = wp[769], w22 = wp[770];

    const float c = w11;
    const int b00 = w00 >= c, b01 = w01 >= c, b02 = w02 >= c;
    const int b10 = w10 >= c,                 b12 = w12 >= c;
    const int b20 = w20 >= c, b21 = w21 >= c, b22 = w22 >= c;

    // LBP keys of the 4 rotations (weights [[1,2,4],[8,0,16],[32,64,128]]).
    const int k0 = b00 + b01*2 + b02*4 + b10*8 + b12*16 + b20*32 + b21*64 + b22*128;
    const int k1 = b02 + b12*2 + b22*4 + b01*8 + b21*16 + b00*32 + b10*64 + b20*128;
    const int k2 = b22 + b21*2 + b20*4 + b12*8 + b10*16 + b02*32 + b01*64 + b00*128;
    const int k3 = b20 + b10*2 + b00*4 + b21*8 + b01*16 + b22*32 + b12*64 + b02*128;

    // First-occurrence argmin (matches jnp.argmin tie-breaking).
    int idx = 0, km = k0;
    if (k1 < km) { km = k1; idx = 1; }
    if (k2 < km) { km = k2; idx = 2; }
    if (k3 < km) { km = k3; idx = 3; }

#define SEL4(a, b, cc, d) (idx == 0 ? (a) : idx == 1 ? (b) : idx == 2 ? (cc) : (d))
    wp[0]   = SEL4(w00, w02, w22, w20);
    wp[1]   = SEL4(w01, w12, w21, w10);
    wp[2]   = SEL4(w02, w22, w20, w00);
    wp[384] = SEL4(w10, w01, w12, w21);
    // wp[385] = w11 (center) — already in place.
    wp[386] = SEL4(w12, w21, w10, w01);
    wp[768] = SEL4(w20, w00, w02, w22);
    wp[769] = SEL4(w21, w10, w01, w12);
    wp[770] = SEL4(w22, w20, w00, w02);
#undef SEL4

    __syncthreads();

    // ---- stage out: 576 float4, coalesced, non-temporal ----
    vf4* qv = (vf4*)(out + base);
    __builtin_nontemporal_store(lv[t], qv + t);
    __builtin_nontemporal_store(lv[t + 256], qv + t + 256);
    if (t < 64) __builtin_nontemporal_store(lv[t + 512], qv + t + 512);
}

extern "C" void kernel_launch(void* const* d_in, const int* in_sizes, int n_in,
                              void* d_out, int out_size, void* d_ws, size_t ws_size,
                              hipStream_t stream) {
    const float* x = (const float*)d_in[0];
    float* out = (float*)d_out;
    const int total = in_sizes[0];          // 8*64*384*384 = 75497472
    const int grid = total / 2304;          // 32768 blocks
    lbp_lds<<<grid, 256, 0, stream>>>(x, out);
}